// Round 1
// baseline (450.555 us; speedup 1.0000x reference)
//
#include <hip/hip_runtime.h>
#include <stdint.h>

#define DEPTHC 2
#define DIMC   512
#define FFC    2048
#define INNERC 32
#define VOCABC 8192
#define BC     2
#define LC     512
#define NTOK   1024   // B*L

typedef _Float16 f16;
typedef __attribute__((ext_vector_type(8))) _Float16 f16x8;
typedef __attribute__((ext_vector_type(4))) float f32x4;

__device__ __forceinline__ float2 cmul2(float2 a, float2 b){
    return make_float2(a.x*b.x - a.y*b.y, a.x*b.y + a.y*b.x);
}
__device__ __forceinline__ float2 cadd2(float2 a, float2 b){
    return make_float2(a.x + b.x, a.y + b.y);
}

// ---------------- fp32 -> fp16 convert (vectorized x4) ----------------
__global__ void k_f2h(const float* __restrict__ in, f16* __restrict__ out, int n){
    int i = (blockIdx.x * 256 + threadIdx.x) * 4;
    if (i >= n) return;
    float4 v = *(const float4*)(in + i);
    union { f16 h[4]; float2 f2; } u;
    u.h[0] = (f16)v.x; u.h[1] = (f16)v.y; u.h[2] = (f16)v.z; u.h[3] = (f16)v.w;
    *(float2*)(out + i) = u.f2;
}

// ---------------- complex 32x32 inverse, fp64 Gauss-Jordan w/ partial pivot ----------------
__global__ void k_inv(const float* __restrict__ v_re, const float* __restrict__ v_im,
                      float2* __restrict__ vinv){
    int d = blockIdx.x;
    __shared__ double Mr[32][64];
    __shared__ double Mi[32][64];
    __shared__ int piv_s;
    __shared__ double ipr_s, ipi_s;
    __shared__ double fr_s[32], fi_s[32];
    int tid = threadIdx.x; // 256
    for (int idx = tid; idx < 2048; idx += 256){
        int r = idx >> 6, c = idx & 63;
        double re, im;
        if (c < 32){ re = (double)v_re[d*1024 + r*32 + c]; im = (double)v_im[d*1024 + r*32 + c]; }
        else { re = (c - 32 == r) ? 1.0 : 0.0; im = 0.0; }
        Mr[r][c] = re; Mi[r][c] = im;
    }
    __syncthreads();
    for (int col = 0; col < 32; ++col){
        if (tid < 64){
            double m = -1.0; int idx = col;
            if (tid >= col && tid < 32){ m = Mr[tid][col]*Mr[tid][col] + Mi[tid][col]*Mi[tid][col]; idx = tid; }
            for (int off = 32; off; off >>= 1){
                double om = __shfl_xor(m, off, 64);
                int    oi = __shfl_xor(idx, off, 64);
                if (om > m){ m = om; idx = oi; }
            }
            if (tid == 0) piv_s = idx;
        }
        __syncthreads();
        int p = piv_s;
        if (p != col && tid < 64){
            double tr = Mr[col][tid]; Mr[col][tid] = Mr[p][tid]; Mr[p][tid] = tr;
            double ti = Mi[col][tid]; Mi[col][tid] = Mi[p][tid]; Mi[p][tid] = ti;
        }
        __syncthreads();
        if (tid == 0){
            double pr = Mr[col][col], pi = Mi[col][col];
            double dm = pr*pr + pi*pi;
            ipr_s = pr/dm; ipi_s = -pi/dm;
        }
        __syncthreads();
        if (tid < 64){
            double r0 = Mr[col][tid], i0 = Mi[col][tid];
            Mr[col][tid] = r0*ipr_s - i0*ipi_s;
            Mi[col][tid] = r0*ipi_s + i0*ipr_s;
        }
        __syncthreads();
        if (tid < 32){ fr_s[tid] = Mr[tid][col]; fi_s[tid] = Mi[tid][col]; }
        __syncthreads();
        for (int idx = tid; idx < 2048; idx += 256){
            int r = idx >> 6, c = idx & 63;
            if (r != col){
                double fr = fr_s[r], fi = fi_s[r];
                double pr = Mr[col][c], pi = Mi[col][c];
                Mr[r][c] -= fr*pr - fi*pi;
                Mi[r][c] -= fr*pi + fi*pr;
            }
        }
        __syncthreads();
    }
    for (int idx = tid; idx < 1024; idx += 256){
        int r = idx >> 5, c = idx & 31;
        vinv[d*1024 + idx] = make_float2((float)Mr[r][32 + c], (float)Mi[r][32 + c]);
    }
}

// ---------------- fp16 MFMA GEMM: C[M,N] = A[M,K] * B[N,K]^T (both K-major) ----------------
// 64x64 block tile, 4 waves each 32x32 (2x2 of 16x16x32 mfma). Optional split-K partials.
__global__ __launch_bounds__(256) void k_gemm(
    const f16* __restrict__ A, const f16* __restrict__ Bw,
    float* __restrict__ C, const float* __restrict__ bias,
    int N, int K, int klen, int partStride)
{
    __shared__ __align__(16) f16 As[64*32];
    __shared__ __align__(16) f16 Bs[64*32];
    const int tid = threadIdx.x;
    const int m0 = blockIdx.y * 64;
    const int n0 = blockIdx.x * 64;
    const int kbeg = blockIdx.z * klen;
    const int l = tid & 63;
    const int w = tid >> 6;
    const int fr = l & 15;
    const int fq = l >> 4;
    const int wm = (w >> 1) * 32;
    const int wn = (w & 1) * 32;
    const f16* ga = A  + (size_t)(m0 + (tid >> 2)) * K + kbeg + (tid & 3) * 8;
    const f16* gb = Bw + (size_t)(n0 + (tid >> 2)) * K + kbeg + (tid & 3) * 8;
    f16* lA = As + tid * 8;
    f16* lB = Bs + tid * 8;
    f32x4 acc[2][2];
#pragma unroll
    for (int i = 0; i < 2; ++i)
#pragma unroll
        for (int j = 0; j < 2; ++j)
            acc[i][j] = (f32x4){0.f, 0.f, 0.f, 0.f};
    for (int kk = 0; kk < klen; kk += 32){
        f16x8 sa = *(const f16x8*)ga;
        f16x8 sb = *(const f16x8*)gb;
        ga += 32; gb += 32;
        __syncthreads();
        *(f16x8*)lA = sa;
        *(f16x8*)lB = sb;
        __syncthreads();
        f16x8 a0 = *(const f16x8*)(As + (wm +      fr) * 32 + fq * 8);
        f16x8 a1 = *(const f16x8*)(As + (wm + 16 + fr) * 32 + fq * 8);
        f16x8 b0 = *(const f16x8*)(Bs + (wn +      fr) * 32 + fq * 8);
        f16x8 b1 = *(const f16x8*)(Bs + (wn + 16 + fr) * 32 + fq * 8);
        acc[0][0] = __builtin_amdgcn_mfma_f32_16x16x32_f16(a0, b0, acc[0][0], 0, 0, 0);
        acc[0][1] = __builtin_amdgcn_mfma_f32_16x16x32_f16(a0, b1, acc[0][1], 0, 0, 0);
        acc[1][0] = __builtin_amdgcn_mfma_f32_16x16x32_f16(a1, b0, acc[1][0], 0, 0, 0);
        acc[1][1] = __builtin_amdgcn_mfma_f32_16x16x32_f16(a1, b1, acc[1][1], 0, 0, 0);
    }
    float* Cb = C + (partStride ? (size_t)blockIdx.z * partStride : 0);
#pragma unroll
    for (int mi = 0; mi < 2; ++mi)
#pragma unroll
        for (int ni = 0; ni < 2; ++ni)
#pragma unroll
            for (int r = 0; r < 4; ++r){
                int row = m0 + wm + 16*mi + fq*4 + r;   // D row = (lane>>4)*4 + reg
                int col = n0 + wn + 16*ni + fr;         // D col = lane&15
                float v = acc[mi][ni][r];
                if (partStride) Cb[(size_t)row * N + col] = v;
                else            Cb[(size_t)row * N + col] = v + (bias ? bias[col] : 0.f);
            }
}

// ---------------- split-K reduce: out = bias + (res?) + sum_{z<8} part[z] ----------------
__global__ void k_reduce8(float* __restrict__ out, const float* __restrict__ part,
                          const float* __restrict__ bias, const float* __restrict__ res, int n){
    int i = blockIdx.x * 256 + threadIdx.x;
    if (i >= n) return;
    float v = bias[i & (DIMC - 1)];
    if (res) v += res[i];
    float s = 0.f;
#pragma unroll
    for (int z = 0; z < 8; ++z) s += part[(size_t)z * n + i];
    out[i] = v + s;
}

// ---------------- LayerNorm -> fp16 (block per row of 512) ----------------
__global__ void k_ln16(const float* __restrict__ X, const float* __restrict__ g,
                       const float* __restrict__ b, f16* __restrict__ out){
    int row = blockIdx.x;
    int tid = threadIdx.x; // 256
    const float* xr = X + (size_t)row * DIMC;
    float v0 = xr[tid], v1 = xr[tid + 256];
    float s = v0 + v1, q = v0*v0 + v1*v1;
    __shared__ float rs[4], rq[4];
    __shared__ float mean_s, rstd_s;
    for (int off = 32; off; off >>= 1){ s += __shfl_down(s, off, 64); q += __shfl_down(q, off, 64); }
    if ((tid & 63) == 0){ rs[tid >> 6] = s; rq[tid >> 6] = q; }
    __syncthreads();
    if (tid == 0){
        float S = rs[0]+rs[1]+rs[2]+rs[3], Q = rq[0]+rq[1]+rq[2]+rq[3];
        float m = S / DIMC;
        float var = Q / DIMC - m*m;
        mean_s = m; rstd_s = rsqrtf(var + 1e-5f);
    }
    __syncthreads();
    float m = mean_s, rst = rstd_s;
    out[(size_t)row*DIMC + tid]       = (f16)((v0 - m)*rst*g[tid]       + b[tid]);
    out[(size_t)row*DIMC + tid + 256] = (f16)((v1 - m)*rst*g[tid + 256] + b[tid + 256]);
}

// ---------------- fused LN1 + gate projections + gate nonlinearity ----------------
// 4 rows/block, 128 threads. Outputs: a_t [B*I][L] (channel-major), xc [B*L][I].
__global__ __launch_bounds__(128) void k_siogate(
    const float* __restrict__ H, const float* __restrict__ g, const float* __restrict__ b,
    const float* __restrict__ wa, const float* __restrict__ wx,
    float2* __restrict__ a_t, float2* __restrict__ xc)
{
    __shared__ float zs[4][DIMC];
    __shared__ float sc[4][128];
    __shared__ float rs2[2], rq2[2];
    int tid = threadIdx.x;
    int r0 = blockIdx.x * 4;
    for (int gg = 0; gg < 4; ++gg){
        const float* xr = H + (size_t)(r0 + gg) * DIMC;
        float v[4]; float s = 0.f, q = 0.f;
#pragma unroll
        for (int j = 0; j < 4; ++j){ v[j] = xr[tid + 128*j]; s += v[j]; q += v[j]*v[j]; }
        for (int off = 32; off; off >>= 1){ s += __shfl_down(s, off, 64); q += __shfl_down(q, off, 64); }
        if ((tid & 63) == 0){ rs2[tid >> 6] = s; rq2[tid >> 6] = q; }
        __syncthreads();
        float m = (rs2[0] + rs2[1]) / DIMC;
        float var = (rq2[0] + rq2[1]) / DIMC - m*m;
        float rst = rsqrtf(var + 1e-5f);
#pragma unroll
        for (int j = 0; j < 4; ++j){ int c = tid + 128*j; zs[gg][c] = (v[j] - m)*rst*g[c] + b[c]; }
        __syncthreads();
    }
    // 128 dot products per row-group: j<64 -> wa row j, j>=64 -> wx row j-64
    const float* wrow = (tid < 64) ? (wa + (size_t)tid * DIMC) : (wx + (size_t)(tid - 64) * DIMC);
    float dot[4] = {0.f, 0.f, 0.f, 0.f};
    for (int c = 0; c < DIMC; c += 4){
        float4 wv = *(const float4*)(wrow + c);
#pragma unroll
        for (int gg = 0; gg < 4; ++gg){
            float4 zv = *(const float4*)(&zs[gg][c]);
            dot[gg] += wv.x*zv.x + wv.y*zv.y + wv.z*zv.z + wv.w*zv.w;
        }
    }
#pragma unroll
    for (int gg = 0; gg < 4; ++gg) sc[gg][tid] = dot[gg];
    __syncthreads();
    int gg = tid >> 5, k = tid & 31;
    int row = r0 + gg;
    int bb = row >> 9, t = row & 511;
    // a = af * rsqrt(m) * sigmoid(log m);  sigmoid(log m) == m/(1+m)
    float re = sc[gg][2*k], im = sc[gg][2*k + 1];
    float m2 = re*re + im*im;
    float sa = rsqrtf(m2) * (m2 / (1.f + m2));
    a_t[(size_t)(bb*INNERC + k)*LC + t] = make_float2(re*sa, im*sa);
    // xc = xf * rsqrt(mx) * mx == xf * sqrt(mx)
    float xr2 = sc[gg][64 + 2*k], xi2 = sc[gg][64 + 2*k + 1];
    float mx = xr2*xr2 + xi2*xi2;
    float sx = sqrtf(mx);
    xc[(size_t)row*INNERC + k] = make_float2(xr2*sx, xi2*sx);
}

// ---------------- w'[b,k,t] = sum_o Vinv[k,o] * x_roll[b,o,t]  (x_roll[0]=h0) ----------------
__global__ __launch_bounds__(256) void k_wprime(
    const float2* __restrict__ xc, const float2* __restrict__ vinv,
    const float* __restrict__ h0re, const float* __restrict__ h0im,
    float2* __restrict__ w_t)
{
    int tid = threadIdx.x;
    int grp = tid >> 5, k = tid & 31;
    int bt = blockIdx.x * 8 + grp;   // 0..1023
    int bb = bt >> 9, t = bt & 511;
    __shared__ float2 xr[8][32];
    if (t == 0) xr[grp][k] = make_float2(h0re[k], h0im[k]);
    else        xr[grp][k] = xc[(size_t)(bt - 1)*INNERC + k];
    __syncthreads();
    const float2* vr = vinv + k * INNERC;
    float2 acc = make_float2(0.f, 0.f);
#pragma unroll
    for (int o = 0; o < 32; ++o){
        float2 vv = vr[o], xx = xr[grp][o];
        acc.x += vv.x*xx.x - vv.y*xx.y;
        acc.y += vv.x*xx.y + vv.y*xx.x;
    }
    w_t[(size_t)(bb*INNERC + k)*LC + t] = acc;
}

// ---------------- scan e[t] = a[t]*(e[t-1] + w'[t]) via wave affine-compose scan ----------------
__global__ __launch_bounds__(64) void k_scan(
    const float2* __restrict__ a_t, const float2* __restrict__ w_t,
    float2* __restrict__ e)  // out: [B*L][I]
{
    int bk = blockIdx.x;   // b*32 + k
    int l = threadIdx.x;   // 0..63, each owns 8 consecutive t
    int base = bk * LC + l * 8;
    float2 av[8], wv[8];
#pragma unroll
    for (int j = 0; j < 8; ++j){ av[j] = a_t[base + j]; wv[j] = w_t[base + j]; }
    // segment transform T(e) = A*e + B
    float2 A = make_float2(1.f, 0.f), Bc = make_float2(0.f, 0.f);
#pragma unroll
    for (int j = 0; j < 8; ++j){
        Bc = cmul2(av[j], cadd2(Bc, wv[j]));
        A  = cmul2(av[j], A);
    }
    // inclusive Hillis-Steele scan of affine maps across 64 lanes
    for (int off = 1; off < 64; off <<= 1){
        float Apx = __shfl_up(A.x,  off, 64), Apy = __shfl_up(A.y,  off, 64);
        float Bpx = __shfl_up(Bc.x, off, 64), Bpy = __shfl_up(Bc.y, off, 64);
        if (l >= off){
            float2 Ap = make_float2(Apx, Apy), Bp = make_float2(Bpx, Bpy);
            Bc = cadd2(cmul2(A, Bp), Bc);
            A  = cmul2(A, Ap);
        }
    }
    float ex = __shfl_up(Bc.x, 1, 64), ey = __shfl_up(Bc.y, 1, 64);
    float2 ecur = (l == 0) ? make_float2(0.f, 0.f) : make_float2(ex, ey);
    int bb = bk >> 5, k = bk & 31;
    size_t obase = ((size_t)bb*LC + l*8) * INNERC + k;
#pragma unroll
    for (int j = 0; j < 8; ++j){
        ecur = cmul2(av[j], cadd2(ecur, wv[j]));
        e[obase + (size_t)j * INNERC] = ecur;
    }
}

// ---------------- hr = Re(V*e) + Re(xc); out = hr @ w_ol^T + residual ----------------
__global__ __launch_bounds__(128) void k_siout(
    const float2* __restrict__ e, const float2* __restrict__ xc,
    const float* __restrict__ vre, const float* __restrict__ vim,
    const float* __restrict__ wol, const float* __restrict__ res,
    float* __restrict__ out)
{
    int bt = blockIdx.x;
    int tid = threadIdx.x;
    __shared__ float hr[INNERC];
    __shared__ float2 er[INNERC];
    if (tid < 32) er[tid] = e[(size_t)bt*INNERC + tid];
    __syncthreads();
    if (tid < 32){
        const float* vrr = vre + tid*INNERC;
        const float* vir = vim + tid*INNERC;
        float acc = xc[(size_t)bt*INNERC + tid].x;
#pragma unroll
        for (int k2 = 0; k2 < 32; ++k2) acc += vrr[k2]*er[k2].x - vir[k2]*er[k2].y;
        hr[tid] = acc;
    }
    __syncthreads();
#pragma unroll
    for (int j = 0; j < 4; ++j){
        int n = tid + 128*j;
        float val = res[(size_t)bt*DIMC + n];
        const float* wr = wol + (size_t)n * INNERC;
#pragma unroll
        for (int i = 0; i < 32; ++i) val += hr[i]*wr[i];
        out[(size_t)bt*DIMC + n] = val;
    }
}

// ---------------- silu -> fp16 ----------------
__global__ void k_silu(const float* __restrict__ X, f16* __restrict__ out, int n){
    int i = (blockIdx.x * 256 + threadIdx.x) * 4;
    if (i >= n) return;
    float4 v = *(const float4*)(X + i);
    union { f16 h[4]; float2 f2; } u;
    u.h[0] = (f16)(v.x / (1.f + __expf(-v.x)));
    u.h[1] = (f16)(v.y / (1.f + __expf(-v.y)));
    u.h[2] = (f16)(v.z / (1.f + __expf(-v.z)));
    u.h[3] = (f16)(v.w / (1.f + __expf(-v.w)));
    *(float2*)(out + i) = u.f2;
}

extern "C" void kernel_launch(void* const* d_in, const int* in_sizes, int n_in,
                              void* d_out, int out_size, void* d_ws, size_t ws_size,
                              hipStream_t stream)
{
    const float* x     = (const float*)d_in[0];
    const float* w_in  = (const float*)d_in[1];
    const float* b_in  = (const float*)d_in[2];
    const float* ln1_g = (const float*)d_in[3];
    const float* ln1_b = (const float*)d_in[4];
    const float* wa    = (const float*)d_in[5];
    const float* wx    = (const float*)d_in[6];
    const float* v_re  = (const float*)d_in[7];
    const float* v_im  = (const float*)d_in[8];
    const float* h0_re = (const float*)d_in[9];
    const float* h0_im = (const float*)d_in[10];
    const float* w_ol  = (const float*)d_in[11];
    const float* ln2_g = (const float*)d_in[12];
    const float* ln2_b = (const float*)d_in[13];
    const float* w1    = (const float*)d_in[14];
    const float* b1    = (const float*)d_in[15];
    const float* w2    = (const float*)d_in[16];
    const float* b2    = (const float*)d_in[17];
    const float* lnl_g = (const float*)d_in[18];
    const float* lnl_b = (const float*)d_in[19];
    const float* w_out = (const float*)d_in[20];
    const float* b_out = (const float*)d_in[21];

    char* p = (char*)d_ws;
    f16* xb   = (f16*)p;   p += (size_t)NTOK * VOCABC * 2;
    f16* wib  = (f16*)p;   p += (size_t)DIMC * VOCABC * 2;
    f16* wob  = (f16*)p;   p += (size_t)VOCABC * DIMC * 2;
    f16* w1b  = (f16*)p;   p += (size_t)DEPTHC * FFC * DIMC * 2;
    f16* w2b  = (f16*)p;   p += (size_t)DEPTHC * DIMC * FFC * 2;
    float* h1 = (float*)p; p += (size_t)NTOK * DIMC * 4;
    float* h2 = (float*)p; p += (size_t)NTOK * DIMC * 4;
    float* h3 = (float*)p; p += (size_t)NTOK * DIMC * 4;
    f16* zb   = (f16*)p;   p += (size_t)NTOK * DIMC * 2;
    float* ff = (float*)p; p += (size_t)NTOK * FFC * 4;
    f16* ffb  = (f16*)p;   p += (size_t)NTOK * FFC * 2;
    float* pbuf = (float*)p; p += (size_t)8 * NTOK * DIMC * 4;
    float2* a_t = (float2*)p; p += (size_t)BC * INNERC * LC * 8;
    float2* w_t = (float2*)p; p += (size_t)BC * INNERC * LC * 8;
    float2* xc  = (float2*)p; p += (size_t)NTOK * INNERC * 8;
    float2* ev  = (float2*)p; p += (size_t)NTOK * INNERC * 8;
    float2* vinv = (float2*)p; p += (size_t)DEPTHC * INNERC * INNERC * 8;

    int n;
    n = NTOK * VOCABC;       k_f2h<<<n/1024, 256, 0, stream>>>(x, xb, n);
    n = DIMC * VOCABC;       k_f2h<<<n/1024, 256, 0, stream>>>(w_in, wib, n);
    n = DEPTHC * FFC * DIMC; k_f2h<<<n/1024, 256, 0, stream>>>(w1, w1b, n);
    n = DEPTHC * DIMC * FFC; k_f2h<<<n/1024, 256, 0, stream>>>(w2, w2b, n);
    n = VOCABC * DIMC;       k_f2h<<<n/1024, 256, 0, stream>>>(w_out, wob, n);
    k_inv<<<DEPTHC, 256, 0, stream>>>(v_re, v_im, vinv);

    // h1 = x @ w_in^T + b_in  (split-K=8 partials + reduce)
    {
        dim3 g(DIMC/64, NTOK/64, 8);
        k_gemm<<<g, 256, 0, stream>>>(xb, wib, pbuf, nullptr, DIMC, VOCABC, VOCABC/8, NTOK*DIMC);
    }
    k_reduce8<<<(NTOK*DIMC)/256, 256, 0, stream>>>(h1, pbuf, b_in, nullptr, NTOK*DIMC);

    float* cur = h1;
    for (int d = 0; d < DEPTHC; ++d){
        float* hb = (d == 0) ? h2 : h1;
        float* hc = (d == 0) ? h3 : h2;
        k_siogate<<<NTOK/4, 128, 0, stream>>>(cur, ln1_g + d*DIMC, ln1_b + d*DIMC,
                                              wa + (size_t)d*2*INNERC*DIMC,
                                              wx + (size_t)d*2*INNERC*DIMC, a_t, xc);
        k_wprime<<<NTOK/8, 256, 0, stream>>>(xc, vinv + d*INNERC*INNERC,
                                             h0_re + d*INNERC, h0_im + d*INNERC, w_t);
        k_scan<<<BC*INNERC, 64, 0, stream>>>(a_t, w_t, ev);
        k_siout<<<NTOK, 128, 0, stream>>>(ev, xc, v_re + d*INNERC*INNERC, v_im + d*INNERC*INNERC,
                                          w_ol + (size_t)d*DIMC*INNERC, cur, hb);
        k_ln16<<<NTOK, 256, 0, stream>>>(hb, ln2_g + d*DIMC, ln2_b + d*DIMC, zb);
        {
            dim3 g(FFC/64, NTOK/64, 1);
            k_gemm<<<g, 256, 0, stream>>>(zb, w1b + (size_t)d*FFC*DIMC, ff, b1 + d*FFC,
                                          FFC, DIMC, DIMC, 0);
        }
        n = NTOK * FFC; k_silu<<<n/1024, 256, 0, stream>>>(ff, ffb, n);
        {
            dim3 g(DIMC/64, NTOK/64, 8);
            k_gemm<<<g, 256, 0, stream>>>(ffb, w2b + (size_t)d*DIMC*FFC, pbuf, nullptr,
                                          DIMC, FFC, FFC/8, NTOK*DIMC);
        }
        k_reduce8<<<(NTOK*DIMC)/256, 256, 0, stream>>>(hc, pbuf, b2 + d*DIMC, hb, NTOK*DIMC);
        cur = hc;
    }
    k_ln16<<<NTOK, 256, 0, stream>>>(cur, lnl_g, lnl_b, zb);
    {
        dim3 g(VOCABC/64, NTOK/64, 1);
        k_gemm<<<g, 256, 0, stream>>>(zb, wob, (float*)d_out, b_out, VOCABC, DIMC, DIMC, 0);
    }
    (void)in_sizes; (void)n_in; (void)out_size; (void)ws_size;
}